// Round 6
// baseline (443.254 us; speedup 1.0000x reference)
//
#include <hip/hip_runtime.h>
#include <hip/hip_bf16.h>
#include <math.h>

#define HH 128
#define WW 128
#define HW 16384
#define NL 49152        // 3 * H * W lines
#define CC 128
#define NPTS0 32
#define NPTS1 8
#define PI_F 3.14159265358979323846f

typedef __attribute__((ext_vector_type(8))) short short8;
typedef __attribute__((ext_vector_type(4))) float f32x4;

__device__ __forceinline__ ushort f2bf(float f) {
    unsigned u = __builtin_bit_cast(unsigned, f);
    unsigned rounding = 0x7FFFu + ((u >> 16) & 1u);
    return (ushort)((u + rounding) >> 16);
}

__device__ __forceinline__ void gload_lds16(const void* gsrc, void* ldst) {
    __builtin_amdgcn_global_load_lds(
        (const __attribute__((address_space(1))) unsigned int*)gsrc,
        (__attribute__((address_space(3))) unsigned int*)ldst,
        16, 0, 0);
}

__device__ __forceinline__ void unpk(uint2 d, float* f) {
    f[0] = __builtin_bit_cast(float, d.x << 16);
    f[1] = __builtin_bit_cast(float, d.x & 0xFFFF0000u);
    f[2] = __builtin_bit_cast(float, d.y << 16);
    f[3] = __builtin_bit_cast(float, d.y & 0xFFFF0000u);
}

// ---------------------------------------------------------------- lines
__global__ __launch_bounds__(256) void k_lines(
    const float* __restrict__ md, const float* __restrict__ dis,
    const float* __restrict__ res, float* __restrict__ lines)
{
    int g = blockIdx.x * 256 + threadIdx.x;
    if (g >= NL) return;
    int s = g / HW;              // 0,1,2 -> scale -1,0,1
    int pix = g - s * HW;
    float sf = (float)(s - 1);
    int y = pix >> 7, x = pix & 127;

    float md0 = md[pix], md1 = md[HW + pix], md2 = md[2 * HW + pix];
    float d = (dis[pix] + sf * res[pix]) * 5.0f;

    float md_ = (md0 - 0.5f) * (2.0f * PI_F);
    float st_ = md1 * (0.5f * PI_F);
    float ed_ = -md2 * (0.5f * PI_F);
    float cs_md = cosf(md_), ss_md = sinf(md_);
    float cs_st = fmaxf(cosf(st_), 0.001f);
    float ss_st = fmaxf(sinf(st_), 0.001f);
    float cs_ed = fmaxf(cosf(ed_), 0.001f);
    float ss_ed = fminf(sinf(ed_), -0.001f);
    float y_st = ss_st / cs_st;
    float y_ed = ss_ed / cs_ed;
    float x_st = (cs_md - ss_md * y_st) * d;
    float y_s  = (ss_md + cs_md * y_st) * d;
    float x_ed = (cs_md - ss_md * y_ed) * d;
    float y_e  = (ss_md + cs_md * y_ed) * d;

    float4 o;
    o.x = fminf(fmaxf(x_st + (float)x, 0.0f), 127.0f);
    o.y = fminf(fmaxf(y_s  + (float)y, 0.0f), 127.0f);
    o.z = fminf(fmaxf(x_ed + (float)x, 0.0f), 127.0f);
    o.w = fminf(fmaxf(y_e  + (float)y, 0.0f), 127.0f);
    ((float4*)lines)[g] = o;
}

// ---------------------------------- feats (C,HW) f32 -> (HW,C) bf16
__global__ void k_transpose(const float* __restrict__ in, ushort* __restrict__ out)
{
    __shared__ float tile[32][33];
    int cb = blockIdx.x;   // over C/32
    int pb = blockIdx.y;   // over HW/32
    int tx = threadIdx.x, ty = threadIdx.y;
#pragma unroll
    for (int j = 0; j < 32; j += 8)
        tile[ty + j][tx] = in[(size_t)(cb * 32 + ty + j) * HW + pb * 32 + tx];
    __syncthreads();
#pragma unroll
    for (int j = 0; j < 32; j += 8)
        out[(size_t)(pb * 32 + ty + j) * CC + cb * 32 + tx] = f2bf(tile[tx][ty + j]);
}

// ---------------------------------------------------------------- W -> bf16
__global__ void k_cvt(const float* __restrict__ a, const float* __restrict__ b,
                      ushort* __restrict__ oa, ushort* __restrict__ ob, int n)
{
    int i = blockIdx.x * 256 + threadIdx.x;
    if (i < n) { oa[i] = f2bf(a[i]); ob[i] = f2bf(b[i]); }
}

// ---------------------------------------------------------------- pooling
// block = 256 threads = 8 lines x 32 channel-groups.
// Phase B: explicit software pipeline, prefetch distance 4 (register ring,
// statically indexed under full unroll). launch_bounds(256,4) -> ~128 VGPR
// budget so the ring stays in registers and loads stay in flight.
__global__ __launch_bounds__(256, 4) void k_pool(
    const ushort* __restrict__ ft, const float* __restrict__ lines,
    ushort* __restrict__ X)
{
    __shared__ __align__(16) unsigned smeta[2048];   // 8 lines * 32 samples * 8 dwords
    const int t = threadIdx.x;
    const int l_loc = t >> 5, p = t & 31;
    const int gl0 = blockIdx.x * 8;

    // ---- phase A: per-(line,sample) meta, computed exactly once
    {
        float4 L = ((const float4*)lines)[gl0 + l_loc];
        float tf = (float)p * (1.0f / 31.0f);
        float omt = 1.0f - tf;
        float px = L.x * tf + L.z * omt - 0.5f;
        float py = L.y * tf + L.w * omt - 0.5f;
        float px0 = fminf(fmaxf(floorf(px), 0.0f), 127.0f);
        float py0 = fminf(fmaxf(floorf(py), 0.0f), 127.0f);
        float px1 = fminf(px0 + 1.0f, 127.0f);
        float py1 = fminf(py0 + 1.0f, 127.0f);
        int ix0 = (int)px0, iy0 = (int)py0, ix1 = (int)px1, iy1 = (int)py1;
        float4 wv;
        wv.x = (py1 - py) * (px1 - px);   // w00 (y0,x0)
        wv.y = (py  - py0) * (px1 - px);  // w10 (y1,x0)
        wv.z = (py1 - py) * (px  - px0);  // w01 (y0,x1)
        wv.w = (py  - py0) * (px  - px0); // w11 (y1,x1)
        int o00 = (iy0 * WW + ix0) * (CC * 2);
        int dx  = (ix1 - ix0) * (CC * 2);
        int dy  = (iy1 - iy0) * (WW * CC * 2);
        int4 ov;
        ov.x = o00;            // (y0,x0)
        ov.y = o00 + dy;       // (y1,x0)
        ov.z = o00 + dx;       // (y0,x1)
        ov.w = o00 + dy + dx;  // (y1,x1)
        *(float4*)&smeta[t * 8]     = wv;
        *(int4*)  &smeta[t * 8 + 4] = ov;
    }
    __syncthreads();

    // ---- phase B: gather + bilinear + max-pool, prefetch distance 4
    const int c4 = p;  // channel group: channels c4*4 .. c4*4+3
    const unsigned coff = (unsigned)(c4 * 8);
    const char* fbase = (const char*)ft;
    float m[4][8];
#pragma unroll
    for (int ch = 0; ch < 4; ++ch)
#pragma unroll
        for (int g = 0; g < 8; ++g) m[ch][g] = -INFINITY;

    float4 wq[4];
    uint2  dq[4][4];
#define PLOAD(s, slot) { \
    const unsigned* mp_ = &smeta[(l_loc * 32 + (s)) * 8]; \
    wq[slot] = *(const float4*)mp_; \
    int4 ov_ = *(const int4*)(mp_ + 4); \
    dq[slot][0] = *(const uint2*)(fbase + ((unsigned)ov_.x + coff)); \
    dq[slot][1] = *(const uint2*)(fbase + ((unsigned)ov_.y + coff)); \
    dq[slot][2] = *(const uint2*)(fbase + ((unsigned)ov_.z + coff)); \
    dq[slot][3] = *(const uint2*)(fbase + ((unsigned)ov_.w + coff)); }

    PLOAD(0, 0) PLOAD(1, 1) PLOAD(2, 2) PLOAD(3, 3)

#pragma unroll
    for (int pp = 0; pp < 32; ++pp) {
        const int slot = pp & 3;           // compile-time under full unroll
        float4 wv = wq[slot];
        float f00[4], f10[4], f01[4], f11[4];
        unpk(dq[slot][0], f00); unpk(dq[slot][1], f10);
        unpk(dq[slot][2], f01); unpk(dq[slot][3], f11);
        if (pp < 28) PLOAD(pp + 4, slot)
#pragma unroll
        for (int ch = 0; ch < 4; ++ch) {
            float v = f00[ch] * wv.x + f10[ch] * wv.y
                    + f01[ch] * wv.z + f11[ch] * wv.w;
            m[ch][pp >> 2] = fmaxf(m[ch][pp >> 2], v);
        }
    }
#undef PLOAD

    ushort* Xp = X + (size_t)(gl0 + l_loc) * 1024 + c4 * 32;
#pragma unroll
    for (int ch = 0; ch < 4; ++ch) {
        short8 pk;
#pragma unroll
        for (int g = 0; g < 8; ++g) pk[g] = (short)f2bf(m[ch][g]);
        *(short8*)(Xp + ch * 8) = pk;
    }
}

// ---------------------------------------------------------------- GEMM 256x256
// Deep-pipelined: BK=32, 4-slot LDS ring per operand, counted vmcnt(6),
// raw s_barrier (1/phase), T2 granule-XOR swizzle, T5 setprio, T1 XCD swizzle.
// A: MxK bf16 row-major, B: NxK bf16 row-major. 512 threads = 8 waves (2Mx4N).
// EPI=0: relu -> store bf16 Y.  EPI=1: relu -> dot w3 -> atomicAdd logits.
#define NT 32            // K / 32
template<int EPI>
__global__ __launch_bounds__(512, 2) void k_gemm2(
    const ushort* __restrict__ A, const ushort* __restrict__ B,
    const float* __restrict__ bias, ushort* __restrict__ Y,
    const float* __restrict__ w3, float* __restrict__ logits,
    int M, int N, int K)
{
    __shared__ __align__(16) ushort lds[65536];   // A: [0,32768), B: [32768,65536)
    const int tid = threadIdx.x;
    const int w = tid >> 6, l = tid & 63;
    const int lr = l & 15, kq = l >> 4;
    const int wm = w >> 2, wn = w & 3;

    // T1: bijective XCD swizzle (gridDim.x % 8 == 0)
    const int nwg = gridDim.x;
    const int cpx = nwg >> 3;
    const int swz = (blockIdx.x & 7) * cpx + (blockIdx.x >> 3);
    const int nbm = M >> 8;
    const int m_blk = swz % nbm;
    const int n_blk = swz / nbm;
    const int m0 = m_blk << 8, n0 = n_blk << 8;

    // staging source precompute. granule G = q*512+tid of a 256x32 tile;
    // row r = G>>2; source granule = (G&3) ^ ((r>>1)&3)  (T2 inverse swizzle)
    const int G0 = tid, G1 = 512 + tid;
    const int r0 = G0 >> 2, r1 = G1 >> 2;
    const int g0 = (G0 & 3) ^ ((r0 >> 1) & 3);
    const int g1 = (G1 & 3) ^ ((r1 >> 1) & 3);
    const ushort* sA0 = A + (size_t)(m0 + r0) * K + g0 * 8;
    const ushort* sA1 = A + (size_t)(m0 + r1) * K + g1 * 8;
    const ushort* sB0 = B + (size_t)(n0 + r0) * K + g0 * 8;
    const ushort* sB1 = B + (size_t)(n0 + r1) * K + g1 * 8;
    ushort* dA0 = &lds[G0 * 8];
    ushort* dA1 = &lds[G1 * 8];
    ushort* dB0 = &lds[32768 + G0 * 8];
    ushort* dB1 = &lds[32768 + G1 * 8];

#define STAGE_A(tp) { int sb = ((tp) & 3) * 8192; \
    gload_lds16(sA0 + (tp) * 32, dA0 + sb); \
    gload_lds16(sA1 + (tp) * 32, dA1 + sb); }
#define STAGE_B(tp) { int sb = ((tp) & 3) * 8192; \
    gload_lds16(sB0 + (tp) * 32, dB0 + sb); \
    gload_lds16(sB1 + (tp) * 32, dB1 + sb); }
#define SBAR  { __builtin_amdgcn_sched_barrier(0); __builtin_amdgcn_s_barrier(); \
                __builtin_amdgcn_sched_barrier(0); }

    // swizzled ds_read offsets (ushort units)
    int aidx[8], bidx[4];
#pragma unroll
    for (int m = 0; m < 8; ++m) {
        int r = wm * 128 + m * 16 + lr;
        int g = kq ^ ((r >> 1) & 3);
        aidx[m] = r * 32 + g * 8;
    }
#pragma unroll
    for (int n = 0; n < 4; ++n) {
        int r = wn * 64 + n * 16 + lr;
        int g = kq ^ ((r >> 1) & 3);
        bidx[n] = 32768 + r * 32 + g * 8;
    }

    f32x4 acc[8][4] = {};

    // prologue: items A0 B0 A1 B1 A2 (10 loads) -> tile0 ready, 6 in flight
    STAGE_A(0); STAGE_B(0); STAGE_A(1); STAGE_B(1); STAGE_A(2);
    asm volatile("s_waitcnt vmcnt(6)" ::: "memory");
    SBAR;

    for (int t = 0; t < NT; ++t) {
        const int sb = (t & 3) * 8192;
        // ---- phase h0: B-frags + A m0-3, MFMA quadrant m0-3
        short8 bq0 = *(const short8*)&lds[sb + bidx[0]];
        short8 bq1 = *(const short8*)&lds[sb + bidx[1]];
        short8 bq2 = *(const short8*)&lds[sb + bidx[2]];
        short8 bq3 = *(const short8*)&lds[sb + bidx[3]];
        short8 a0 = *(const short8*)&lds[sb + aidx[0]];
        short8 a1 = *(const short8*)&lds[sb + aidx[1]];
        short8 a2 = *(const short8*)&lds[sb + aidx[2]];
        short8 a3 = *(const short8*)&lds[sb + aidx[3]];
        if (t + 2 < NT) STAGE_B(t + 2);
        __builtin_amdgcn_s_setprio(1);
#pragma unroll
        for (int n = 0; n < 4; ++n) {
            short8 bn = (n == 0) ? bq0 : (n == 1) ? bq1 : (n == 2) ? bq2 : bq3;
            acc[0][n] = __builtin_amdgcn_mfma_f32_16x16x32_bf16(a0, bn, acc[0][n], 0, 0, 0);
            acc[1][n] = __builtin_amdgcn_mfma_f32_16x16x32_bf16(a1, bn, acc[1][n], 0, 0, 0);
            acc[2][n] = __builtin_amdgcn_mfma_f32_16x16x32_bf16(a2, bn, acc[2][n], 0, 0, 0);
            acc[3][n] = __builtin_amdgcn_mfma_f32_16x16x32_bf16(a3, bn, acc[3][n], 0, 0, 0);
        }
        __builtin_amdgcn_s_setprio(0);
        SBAR;
        // ---- phase h1: A m4-7, MFMA quadrant m4-7
        short8 a4 = *(const short8*)&lds[sb + aidx[4]];
        short8 a5 = *(const short8*)&lds[sb + aidx[5]];
        short8 a6 = *(const short8*)&lds[sb + aidx[6]];
        short8 a7 = *(const short8*)&lds[sb + aidx[7]];
        if (t + 3 < NT) STAGE_A(t + 3);
        __builtin_amdgcn_s_setprio(1);
#pragma unroll
        for (int n = 0; n < 4; ++n) {
            short8 bn = (n == 0) ? bq0 : (n == 1) ? bq1 : (n == 2) ? bq2 : bq3;
            acc[4][n] = __builtin_amdgcn_mfma_f32_16x16x32_bf16(a4, bn, acc[4][n], 0, 0, 0);
            acc[5][n] = __builtin_amdgcn_mfma_f32_16x16x32_bf16(a5, bn, acc[5][n], 0, 0, 0);
            acc[6][n] = __builtin_amdgcn_mfma_f32_16x16x32_bf16(a6, bn, acc[6][n], 0, 0, 0);
            acc[7][n] = __builtin_amdgcn_mfma_f32_16x16x32_bf16(a7, bn, acc[7][n], 0, 0, 0);
        }
        __builtin_amdgcn_s_setprio(0);
        // tile t+1 must be ready for next iteration
        if (t < NT - 3) {
            asm volatile("s_waitcnt vmcnt(6)" ::: "memory");
        } else {
            asm volatile("s_waitcnt vmcnt(0)" ::: "memory");
        }
        SBAR;
    }
#undef STAGE_A
#undef STAGE_B
#undef SBAR

    // ---------------- epilogue
    if (EPI == 0) {
        float bv[4];
#pragma unroll
        for (int n = 0; n < 4; ++n) bv[n] = bias[n0 + wn * 64 + n * 16 + lr];
#pragma unroll
        for (int m = 0; m < 8; ++m) {
#pragma unroll
            for (int n = 0; n < 4; ++n) {
                int col = n0 + wn * 64 + n * 16 + lr;
#pragma unroll
                for (int j = 0; j < 4; ++j) {
                    int row = m0 + wm * 128 + m * 16 + kq * 4 + j;
                    float v = fmaxf(acc[m][n][j] + bv[n], 0.0f);
                    Y[(size_t)row * N + col] = f2bf(v);
                }
            }
        }
    } else {
        float w3v[4], bv[4];
#pragma unroll
        for (int n = 0; n < 4; ++n) {
            int col = n0 + wn * 64 + n * 16 + lr;
            w3v[n] = w3[col];
            bv[n] = bias[col];
        }
#pragma unroll
        for (int m = 0; m < 8; ++m) {
#pragma unroll
            for (int j = 0; j < 4; ++j) {
                float s = 0.0f;
#pragma unroll
                for (int n = 0; n < 4; ++n)
                    s += fmaxf(acc[m][n][j] + bv[n], 0.0f) * w3v[n];
#pragma unroll
                for (int off = 1; off < 16; off <<= 1)
                    s += __shfl_xor(s, off, 64);
                if (lr == 0)
                    atomicAdd(&logits[m0 + wm * 128 + m * 16 + kq * 4 + j], s);
            }
        }
    }
}

// ---------------------------------------------------------------- logits = b3
__global__ void k_init_logits(float* __restrict__ logits, const float* __restrict__ b3, int n)
{
    int i = blockIdx.x * 256 + threadIdx.x;
    if (i < n) logits[i] = b3[0];
}

// --------------------------------------------- NMS + per-chunk top-50
// key = (valbits << 32) | (0xFFFFFFFF - idx): u64 descending sort ==
// value desc, index asc (exact lax.top_k tie semantics). values >= 0.
__global__ __launch_bounds__(256) void k_nms_topk(
    const float* __restrict__ jloc, unsigned long long* __restrict__ cand)
{
    __shared__ unsigned long long sk[256];
    const int t = threadIdx.x;
    const int idx = blockIdx.x * 256 + t;      // 64 chunks x 2 rows
    const int y = idx >> 7, x = idx & 127;
    float cv = jloc[idx];
    float m = cv;
    for (int dy = -1; dy <= 1; ++dy) {
        int yy = y + dy;
        if (yy < 0 || yy > 127) continue;
        for (int dx = -1; dx <= 1; ++dx) {
            int xx = x + dx;
            if (xx < 0 || xx > 127) continue;
            m = fmaxf(m, jloc[(yy << 7) + xx]);
        }
    }
    float nv = (cv == m) ? cv : 0.0f;
    unsigned vb = __builtin_bit_cast(unsigned, nv);
    sk[t] = ((unsigned long long)vb << 32) | (unsigned)(0xFFFFFFFFu - idx);
    __syncthreads();
    // bitonic sort, descending
    for (int k = 2; k <= 256; k <<= 1) {
        for (int j = k >> 1; j >= 1; j >>= 1) {
            int ixj = t ^ j;
            if (ixj > t) {
                unsigned long long a = sk[t], b = sk[ixj];
                bool up = ((t & k) == 0);
                if (up ? (a < b) : (a > b)) { sk[t] = b; sk[ixj] = a; }
            }
            __syncthreads();
        }
    }
    if (t < 64) cand[blockIdx.x * 64 + t] = (t < 50) ? sk[t] : 0ull;
}

// --------------------------------------------- merge 64x50 -> top-50 + junctions
__global__ __launch_bounds__(1024) void k_topk_final(
    const unsigned long long* __restrict__ cand,
    const float* __restrict__ joff, float* __restrict__ outj)
{
    __shared__ unsigned long long sk[4096];
    const int t = threadIdx.x;
#pragma unroll
    for (int e = 0; e < 4; ++e) sk[t + (e << 10)] = cand[t + (e << 10)];
    __syncthreads();
    for (int k = 2; k <= 4096; k <<= 1) {
        for (int j = k >> 1; j >= 1; j >>= 1) {
#pragma unroll
            for (int e = 0; e < 4; ++e) {
                int i = t + (e << 10);
                int ixj = i ^ j;
                if (ixj > i) {
                    unsigned long long a = sk[i], b = sk[ixj];
                    bool up = ((i & k) == 0);
                    if (up ? (a < b) : (a > b)) { sk[i] = b; sk[ixj] = a; }
                }
            }
            __syncthreads();
        }
    }
    if (t < 50) {
        unsigned long long kk = sk[t];
        unsigned idx = 0xFFFFFFFFu - (unsigned)(kk & 0xFFFFFFFFull);
        float val = __builtin_bit_cast(float, (unsigned)(kk >> 32));
        int y = idx >> 7, x = idx & 127;
        outj[2 * t]     = (float)x + joff[idx]      + 0.5f;
        outj[2 * t + 1] = (float)y + joff[HW + idx] + 0.5f;
        outj[100 + t]   = val;
    }
}

// ---------------------------------------------------------------- launch
extern "C" void kernel_launch(void* const* d_in, const int* in_sizes, int n_in,
                              void* d_out, int out_size, void* d_ws, size_t ws_size,
                              hipStream_t stream) {
    const float* md   = (const float*)d_in[0];
    const float* dis  = (const float*)d_in[1];
    const float* res  = (const float*)d_in[2];
    const float* jloc = (const float*)d_in[3];
    const float* joff = (const float*)d_in[4];
    const float* feats= (const float*)d_in[5];
    const float* W1   = (const float*)d_in[6];
    const float* b1   = (const float*)d_in[7];
    const float* W2   = (const float*)d_in[8];
    const float* b2   = (const float*)d_in[9];
    const float* W3   = (const float*)d_in[10];
    const float* b3   = (const float*)d_in[11];
    float* out = (float*)d_out;

    char* ws = (char*)d_ws;
    size_t off = 0;
    auto alloc = [&](size_t bytes) {
        void* p = ws + off;
        off = (off + bytes + 255) & ~(size_t)255;
        return p;
    };
    float*  lines = (float*) alloc((size_t)NL * 4 * sizeof(float));
    ushort* ft    = (ushort*)alloc((size_t)HW * CC * 2);
    ushort* W1b   = (ushort*)alloc((size_t)1024 * 1024 * 2);
    ushort* W2b   = (ushort*)alloc((size_t)1024 * 1024 * 2);
    ushort* X     = (ushort*)alloc((size_t)NL * 1024 * 2);
    ushort* Y1    = (ushort*)alloc((size_t)NL * 1024 * 2);
    unsigned long long* cand = (unsigned long long*)alloc(4096 * 8);

    k_lines<<<NL / 256, 256, 0, stream>>>(md, dis, res, lines);
    k_transpose<<<dim3(CC / 32, HW / 32), dim3(32, 8), 0, stream>>>(feats, ft);
    k_cvt<<<(1024 * 1024) / 256, 256, 0, stream>>>(W1, W2, W1b, W2b, 1024 * 1024);
    k_pool<<<NL / 8, 256, 0, stream>>>(ft, lines, X);

    int ngrid = (NL / 256) * (1024 / 256);   // 768, divisible by 8
    k_gemm2<0><<<ngrid, 512, 0, stream>>>(X, W1b, b1, Y1, nullptr, nullptr, NL, 1024, 1024);
    k_init_logits<<<NL / 256, 256, 0, stream>>>(out, b3, NL);
    k_gemm2<1><<<ngrid, 512, 0, stream>>>(Y1, W2b, b2, nullptr, W3, out, NL, 1024, 1024);

    k_nms_topk<<<64, 256, 0, stream>>>(jloc, cand);
    k_topk_final<<<1, 1024, 0, stream>>>(cand, joff, out + NL);
}

// Round 7
// 374.460 us; speedup vs baseline: 1.1837x; 1.1837x over previous
//
#include <hip/hip_runtime.h>
#include <hip/hip_bf16.h>
#include <math.h>

#define HH 128
#define WW 128
#define HW 16384
#define NL 49152        // 3 * H * W lines
#define CC 128
#define NPTS0 32
#define NPTS1 8
#define PI_F 3.14159265358979323846f

typedef __attribute__((ext_vector_type(8))) short short8;
typedef __attribute__((ext_vector_type(4))) float f32x4;

__device__ __forceinline__ ushort f2bf(float f) {
    unsigned u = __builtin_bit_cast(unsigned, f);
    unsigned rounding = 0x7FFFu + ((u >> 16) & 1u);
    return (ushort)((u + rounding) >> 16);
}

__device__ __forceinline__ void gload_lds16(const void* gsrc, void* ldst) {
    __builtin_amdgcn_global_load_lds(
        (const __attribute__((address_space(1))) unsigned int*)gsrc,
        (__attribute__((address_space(3))) unsigned int*)ldst,
        16, 0, 0);
}

__device__ __forceinline__ void unpk8(uint4 d, float* f) {
    f[0] = __builtin_bit_cast(float, d.x << 16);
    f[1] = __builtin_bit_cast(float, d.x & 0xFFFF0000u);
    f[2] = __builtin_bit_cast(float, d.y << 16);
    f[3] = __builtin_bit_cast(float, d.y & 0xFFFF0000u);
    f[4] = __builtin_bit_cast(float, d.z << 16);
    f[5] = __builtin_bit_cast(float, d.z & 0xFFFF0000u);
    f[6] = __builtin_bit_cast(float, d.w << 16);
    f[7] = __builtin_bit_cast(float, d.w & 0xFFFF0000u);
}

// ---------------------------------------------------------------- lines
__global__ __launch_bounds__(256) void k_lines(
    const float* __restrict__ md, const float* __restrict__ dis,
    const float* __restrict__ res, float* __restrict__ lines)
{
    int g = blockIdx.x * 256 + threadIdx.x;
    if (g >= NL) return;
    int s = g / HW;              // 0,1,2 -> scale -1,0,1
    int pix = g - s * HW;
    float sf = (float)(s - 1);
    int y = pix >> 7, x = pix & 127;

    float md0 = md[pix], md1 = md[HW + pix], md2 = md[2 * HW + pix];
    float d = (dis[pix] + sf * res[pix]) * 5.0f;

    float md_ = (md0 - 0.5f) * (2.0f * PI_F);
    float st_ = md1 * (0.5f * PI_F);
    float ed_ = -md2 * (0.5f * PI_F);
    float cs_md = cosf(md_), ss_md = sinf(md_);
    float cs_st = fmaxf(cosf(st_), 0.001f);
    float ss_st = fmaxf(sinf(st_), 0.001f);
    float cs_ed = fmaxf(cosf(ed_), 0.001f);
    float ss_ed = fminf(sinf(ed_), -0.001f);
    float y_st = ss_st / cs_st;
    float y_ed = ss_ed / cs_ed;
    float x_st = (cs_md - ss_md * y_st) * d;
    float y_s  = (ss_md + cs_md * y_st) * d;
    float x_ed = (cs_md - ss_md * y_ed) * d;
    float y_e  = (ss_md + cs_md * y_ed) * d;

    float4 o;
    o.x = fminf(fmaxf(x_st + (float)x, 0.0f), 127.0f);
    o.y = fminf(fmaxf(y_s  + (float)y, 0.0f), 127.0f);
    o.z = fminf(fmaxf(x_ed + (float)x, 0.0f), 127.0f);
    o.w = fminf(fmaxf(y_e  + (float)y, 0.0f), 127.0f);
    ((float4*)lines)[g] = o;
}

// ---------------------------------- feats (C,HW) f32 -> (HW,C) bf16
__global__ void k_transpose(const float* __restrict__ in, ushort* __restrict__ out)
{
    __shared__ float tile[32][33];
    int cb = blockIdx.x;   // over C/32
    int pb = blockIdx.y;   // over HW/32
    int tx = threadIdx.x, ty = threadIdx.y;
#pragma unroll
    for (int j = 0; j < 32; j += 8)
        tile[ty + j][tx] = in[(size_t)(cb * 32 + ty + j) * HW + pb * 32 + tx];
    __syncthreads();
#pragma unroll
    for (int j = 0; j < 32; j += 8)
        out[(size_t)(pb * 32 + ty + j) * CC + cb * 32 + tx] = f2bf(tile[tx][ty + j]);
}

// ---------------------------------------------------------------- W -> bf16
__global__ void k_cvt(const float* __restrict__ a, const float* __restrict__ b,
                      ushort* __restrict__ oa, ushort* __restrict__ ob, int n)
{
    int i = blockIdx.x * 256 + threadIdx.x;
    if (i < n) { oa[i] = f2bf(a[i]); ob[i] = f2bf(b[i]); }
}

// ---------------------------------------------------------------- pooling
// block = 128 threads = 8 lines x 16 channel-groups-of-8.
// uint4 (16B) corner loads halve vmem instruction count vs uint2 version.
// m[8][8] accumulator fully statically indexed (nested full unroll).
__global__ __launch_bounds__(128, 4) void k_pool(
    const ushort* __restrict__ ft, const float* __restrict__ lines,
    ushort* __restrict__ X)
{
    __shared__ __align__(16) unsigned smeta[2048];   // 8 lines * 32 samples * 8 dwords
    const int t = threadIdx.x;
    const int l_loc = t >> 4, c8 = t & 15;
    const int gl0 = blockIdx.x * 8;

    // ---- phase A: per-(line,sample) meta, computed exactly once (2/thread)
#pragma unroll
    for (int e = 0; e < 2; ++e) {
        int s = t + e * 128;
        int ml = s >> 5, sp = s & 31;
        float4 L = ((const float4*)lines)[gl0 + ml];
        float tf = (float)sp * (1.0f / 31.0f);
        float omt = 1.0f - tf;
        float px = L.x * tf + L.z * omt - 0.5f;
        float py = L.y * tf + L.w * omt - 0.5f;
        float px0 = fminf(fmaxf(floorf(px), 0.0f), 127.0f);
        float py0 = fminf(fmaxf(floorf(py), 0.0f), 127.0f);
        float px1 = fminf(px0 + 1.0f, 127.0f);
        float py1 = fminf(py0 + 1.0f, 127.0f);
        int ix0 = (int)px0, iy0 = (int)py0, ix1 = (int)px1, iy1 = (int)py1;
        float4 wv;
        wv.x = (py1 - py) * (px1 - px);   // w00 (y0,x0)
        wv.y = (py  - py0) * (px1 - px);  // w10 (y1,x0)
        wv.z = (py1 - py) * (px  - px0);  // w01 (y0,x1)
        wv.w = (py  - py0) * (px  - px0); // w11 (y1,x1)
        int o00 = (iy0 * WW + ix0) * (CC * 2);
        int dx  = (ix1 - ix0) * (CC * 2);
        int dy  = (iy1 - iy0) * (WW * CC * 2);
        int4 ov;
        ov.x = o00;            // (y0,x0)
        ov.y = o00 + dy;       // (y1,x0)
        ov.z = o00 + dx;       // (y0,x1)
        ov.w = o00 + dy + dx;  // (y1,x1)
        *(float4*)&smeta[s * 8]     = wv;
        *(int4*)  &smeta[s * 8 + 4] = ov;
    }
    __syncthreads();

    // ---- phase B: gather (16B) + bilinear + max-pool
    const unsigned coff = (unsigned)(c8 * 16);
    const char* fbase = (const char*)ft;
    float m[8][8];
#pragma unroll
    for (int ch = 0; ch < 8; ++ch)
#pragma unroll
        for (int g = 0; g < 8; ++g) m[ch][g] = -INFINITY;

#pragma unroll
    for (int g = 0; g < 8; ++g) {
#pragma unroll
        for (int j = 0; j < 4; ++j) {
            const unsigned* mp = &smeta[(l_loc * 32 + g * 4 + j) * 8];
            float4 wv = *(const float4*)mp;
            int4  ov = *(const int4*)(mp + 4);
            uint4 d00 = *(const uint4*)(fbase + ((unsigned)ov.x + coff));
            uint4 d10 = *(const uint4*)(fbase + ((unsigned)ov.y + coff));
            uint4 d01 = *(const uint4*)(fbase + ((unsigned)ov.z + coff));
            uint4 d11 = *(const uint4*)(fbase + ((unsigned)ov.w + coff));
            float f00[8], f10[8], f01[8], f11[8];
            unpk8(d00, f00); unpk8(d10, f10); unpk8(d01, f01); unpk8(d11, f11);
#pragma unroll
            for (int ch = 0; ch < 8; ++ch) {
                float v = f00[ch] * wv.x + f10[ch] * wv.y
                        + f01[ch] * wv.z + f11[ch] * wv.w;
                m[ch][g] = fmaxf(m[ch][g], v);
            }
        }
    }

    ushort* Xp = X + (size_t)(gl0 + l_loc) * 1024 + c8 * 64;
#pragma unroll
    for (int ch = 0; ch < 8; ++ch) {
        short8 pk;
#pragma unroll
        for (int g = 0; g < 8; ++g) pk[g] = (short)f2bf(m[ch][g]);
        *(short8*)(Xp + ch * 8) = pk;
    }
}

// ---------------------------------------------------------------- GEMM 256x256
// Deep-pipelined: BK=32, 4-slot LDS ring per operand, counted vmcnt(6),
// raw s_barrier (1/phase), T2 granule-XOR swizzle, T5 setprio, T1 XCD swizzle.
// A: MxK bf16 row-major, B: NxK bf16 row-major. 512 threads = 8 waves (2Mx4N).
// EPI=0: relu -> store bf16 Y.  EPI=1: relu -> dot w3 -> atomicAdd logits.
#define NT 32            // K / 32
template<int EPI>
__global__ __launch_bounds__(512, 2) void k_gemm2(
    const ushort* __restrict__ A, const ushort* __restrict__ B,
    const float* __restrict__ bias, ushort* __restrict__ Y,
    const float* __restrict__ w3, float* __restrict__ logits,
    int M, int N, int K)
{
    __shared__ __align__(16) ushort lds[65536];   // A: [0,32768), B: [32768,65536)
    const int tid = threadIdx.x;
    const int w = tid >> 6, l = tid & 63;
    const int lr = l & 15, kq = l >> 4;
    const int wm = w >> 2, wn = w & 3;

    // T1: bijective XCD swizzle (gridDim.x % 8 == 0)
    const int nwg = gridDim.x;
    const int cpx = nwg >> 3;
    const int swz = (blockIdx.x & 7) * cpx + (blockIdx.x >> 3);
    const int nbm = M >> 8;
    const int m_blk = swz % nbm;
    const int n_blk = swz / nbm;
    const int m0 = m_blk << 8, n0 = n_blk << 8;

    // staging source precompute. granule G = q*512+tid of a 256x32 tile;
    // row r = G>>2; source granule = (G&3) ^ ((r>>1)&3)  (T2 inverse swizzle)
    const int G0 = tid, G1 = 512 + tid;
    const int r0 = G0 >> 2, r1 = G1 >> 2;
    const int g0 = (G0 & 3) ^ ((r0 >> 1) & 3);
    const int g1 = (G1 & 3) ^ ((r1 >> 1) & 3);
    const ushort* sA0 = A + (size_t)(m0 + r0) * K + g0 * 8;
    const ushort* sA1 = A + (size_t)(m0 + r1) * K + g1 * 8;
    const ushort* sB0 = B + (size_t)(n0 + r0) * K + g0 * 8;
    const ushort* sB1 = B + (size_t)(n0 + r1) * K + g1 * 8;
    ushort* dA0 = &lds[G0 * 8];
    ushort* dA1 = &lds[G1 * 8];
    ushort* dB0 = &lds[32768 + G0 * 8];
    ushort* dB1 = &lds[32768 + G1 * 8];

#define STAGE_A(tp) { int sb = ((tp) & 3) * 8192; \
    gload_lds16(sA0 + (tp) * 32, dA0 + sb); \
    gload_lds16(sA1 + (tp) * 32, dA1 + sb); }
#define STAGE_B(tp) { int sb = ((tp) & 3) * 8192; \
    gload_lds16(sB0 + (tp) * 32, dB0 + sb); \
    gload_lds16(sB1 + (tp) * 32, dB1 + sb); }
#define SBAR  { __builtin_amdgcn_sched_barrier(0); __builtin_amdgcn_s_barrier(); \
                __builtin_amdgcn_sched_barrier(0); }

    // swizzled ds_read offsets (ushort units)
    int aidx[8], bidx[4];
#pragma unroll
    for (int m = 0; m < 8; ++m) {
        int r = wm * 128 + m * 16 + lr;
        int g = kq ^ ((r >> 1) & 3);
        aidx[m] = r * 32 + g * 8;
    }
#pragma unroll
    for (int n = 0; n < 4; ++n) {
        int r = wn * 64 + n * 16 + lr;
        int g = kq ^ ((r >> 1) & 3);
        bidx[n] = 32768 + r * 32 + g * 8;
    }

    f32x4 acc[8][4] = {};

    // prologue: items A0 B0 A1 B1 A2 (10 loads) -> tile0 ready, 6 in flight
    STAGE_A(0); STAGE_B(0); STAGE_A(1); STAGE_B(1); STAGE_A(2);
    asm volatile("s_waitcnt vmcnt(6)" ::: "memory");
    SBAR;

    for (int t = 0; t < NT; ++t) {
        const int sb = (t & 3) * 8192;
        // ---- phase h0: B-frags + A m0-3, MFMA quadrant m0-3
        short8 bq0 = *(const short8*)&lds[sb + bidx[0]];
        short8 bq1 = *(const short8*)&lds[sb + bidx[1]];
        short8 bq2 = *(const short8*)&lds[sb + bidx[2]];
        short8 bq3 = *(const short8*)&lds[sb + bidx[3]];
        short8 a0 = *(const short8*)&lds[sb + aidx[0]];
        short8 a1 = *(const short8*)&lds[sb + aidx[1]];
        short8 a2 = *(const short8*)&lds[sb + aidx[2]];
        short8 a3 = *(const short8*)&lds[sb + aidx[3]];
        if (t + 2 < NT) STAGE_B(t + 2);
        __builtin_amdgcn_s_setprio(1);
#pragma unroll
        for (int n = 0; n < 4; ++n) {
            short8 bn = (n == 0) ? bq0 : (n == 1) ? bq1 : (n == 2) ? bq2 : bq3;
            acc[0][n] = __builtin_amdgcn_mfma_f32_16x16x32_bf16(a0, bn, acc[0][n], 0, 0, 0);
            acc[1][n] = __builtin_amdgcn_mfma_f32_16x16x32_bf16(a1, bn, acc[1][n], 0, 0, 0);
            acc[2][n] = __builtin_amdgcn_mfma_f32_16x16x32_bf16(a2, bn, acc[2][n], 0, 0, 0);
            acc[3][n] = __builtin_amdgcn_mfma_f32_16x16x32_bf16(a3, bn, acc[3][n], 0, 0, 0);
        }
        __builtin_amdgcn_s_setprio(0);
        SBAR;
        // ---- phase h1: A m4-7, MFMA quadrant m4-7
        short8 a4 = *(const short8*)&lds[sb + aidx[4]];
        short8 a5 = *(const short8*)&lds[sb + aidx[5]];
        short8 a6 = *(const short8*)&lds[sb + aidx[6]];
        short8 a7 = *(const short8*)&lds[sb + aidx[7]];
        if (t + 3 < NT) STAGE_A(t + 3);
        __builtin_amdgcn_s_setprio(1);
#pragma unroll
        for (int n = 0; n < 4; ++n) {
            short8 bn = (n == 0) ? bq0 : (n == 1) ? bq1 : (n == 2) ? bq2 : bq3;
            acc[4][n] = __builtin_amdgcn_mfma_f32_16x16x32_bf16(a4, bn, acc[4][n], 0, 0, 0);
            acc[5][n] = __builtin_amdgcn_mfma_f32_16x16x32_bf16(a5, bn, acc[5][n], 0, 0, 0);
            acc[6][n] = __builtin_amdgcn_mfma_f32_16x16x32_bf16(a6, bn, acc[6][n], 0, 0, 0);
            acc[7][n] = __builtin_amdgcn_mfma_f32_16x16x32_bf16(a7, bn, acc[7][n], 0, 0, 0);
        }
        __builtin_amdgcn_s_setprio(0);
        // tile t+1 must be ready for next iteration
        if (t < NT - 3) {
            asm volatile("s_waitcnt vmcnt(6)" ::: "memory");
        } else {
            asm volatile("s_waitcnt vmcnt(0)" ::: "memory");
        }
        SBAR;
    }
#undef STAGE_A
#undef STAGE_B
#undef SBAR

    // ---------------- epilogue
    if (EPI == 0) {
        float bv[4];
#pragma unroll
        for (int n = 0; n < 4; ++n) bv[n] = bias[n0 + wn * 64 + n * 16 + lr];
#pragma unroll
        for (int m = 0; m < 8; ++m) {
#pragma unroll
            for (int n = 0; n < 4; ++n) {
                int col = n0 + wn * 64 + n * 16 + lr;
#pragma unroll
                for (int j = 0; j < 4; ++j) {
                    int row = m0 + wm * 128 + m * 16 + kq * 4 + j;
                    float v = fmaxf(acc[m][n][j] + bv[n], 0.0f);
                    Y[(size_t)row * N + col] = f2bf(v);
                }
            }
        }
    } else {
        float w3v[4], bv[4];
#pragma unroll
        for (int n = 0; n < 4; ++n) {
            int col = n0 + wn * 64 + n * 16 + lr;
            w3v[n] = w3[col];
            bv[n] = bias[col];
        }
#pragma unroll
        for (int m = 0; m < 8; ++m) {
#pragma unroll
            for (int j = 0; j < 4; ++j) {
                float s = 0.0f;
#pragma unroll
                for (int n = 0; n < 4; ++n)
                    s += fmaxf(acc[m][n][j] + bv[n], 0.0f) * w3v[n];
#pragma unroll
                for (int off = 1; off < 16; off <<= 1)
                    s += __shfl_xor(s, off, 64);
                if (lr == 0)
                    atomicAdd(&logits[m0 + wm * 128 + m * 16 + kq * 4 + j], s);
            }
        }
    }
}

// ---------------------------------------------------------------- logits = b3
__global__ void k_init_logits(float* __restrict__ logits, const float* __restrict__ b3, int n)
{
    int i = blockIdx.x * 256 + threadIdx.x;
    if (i < n) logits[i] = b3[0];
}

// --------------------------------------------- NMS + per-chunk top-50
// key = (valbits << 32) | (0xFFFFFFFF - idx): u64 descending sort ==
// value desc, index asc (exact lax.top_k tie semantics). values >= 0.
__global__ __launch_bounds__(256) void k_nms_topk(
    const float* __restrict__ jloc, unsigned long long* __restrict__ cand)
{
    __shared__ unsigned long long sk[256];
    const int t = threadIdx.x;
    const int idx = blockIdx.x * 256 + t;      // 64 chunks x 2 rows
    const int y = idx >> 7, x = idx & 127;
    float cv = jloc[idx];
    float m = cv;
    for (int dy = -1; dy <= 1; ++dy) {
        int yy = y + dy;
        if (yy < 0 || yy > 127) continue;
        for (int dx = -1; dx <= 1; ++dx) {
            int xx = x + dx;
            if (xx < 0 || xx > 127) continue;
            m = fmaxf(m, jloc[(yy << 7) + xx]);
        }
    }
    float nv = (cv == m) ? cv : 0.0f;
    unsigned vb = __builtin_bit_cast(unsigned, nv);
    sk[t] = ((unsigned long long)vb << 32) | (unsigned)(0xFFFFFFFFu - idx);
    __syncthreads();
    // bitonic sort, descending
    for (int k = 2; k <= 256; k <<= 1) {
        for (int j = k >> 1; j >= 1; j >>= 1) {
            int ixj = t ^ j;
            if (ixj > t) {
                unsigned long long a = sk[t], b = sk[ixj];
                bool up = ((t & k) == 0);
                if (up ? (a < b) : (a > b)) { sk[t] = b; sk[ixj] = a; }
            }
            __syncthreads();
        }
    }
    if (t < 64) cand[blockIdx.x * 64 + t] = (t < 50) ? sk[t] : 0ull;
}

// --------------------------------------------- merge 64x50 -> top-50 + junctions
__global__ __launch_bounds__(1024) void k_topk_final(
    const unsigned long long* __restrict__ cand,
    const float* __restrict__ joff, float* __restrict__ outj)
{
    __shared__ unsigned long long sk[4096];
    const int t = threadIdx.x;
#pragma unroll
    for (int e = 0; e < 4; ++e) sk[t + (e << 10)] = cand[t + (e << 10)];
    __syncthreads();
    for (int k = 2; k <= 4096; k <<= 1) {
        for (int j = k >> 1; j >= 1; j >>= 1) {
#pragma unroll
            for (int e = 0; e < 4; ++e) {
                int i = t + (e << 10);
                int ixj = i ^ j;
                if (ixj > i) {
                    unsigned long long a = sk[i], b = sk[ixj];
                    bool up = ((i & k) == 0);
                    if (up ? (a < b) : (a > b)) { sk[i] = b; sk[ixj] = a; }
                }
            }
            __syncthreads();
        }
    }
    if (t < 50) {
        unsigned long long kk = sk[t];
        unsigned idx = 0xFFFFFFFFu - (unsigned)(kk & 0xFFFFFFFFull);
        float val = __builtin_bit_cast(float, (unsigned)(kk >> 32));
        int y = idx >> 7, x = idx & 127;
        outj[2 * t]     = (float)x + joff[idx]      + 0.5f;
        outj[2 * t + 1] = (float)y + joff[HW + idx] + 0.5f;
        outj[100 + t]   = val;
    }
}

// ---------------------------------------------------------------- launch
extern "C" void kernel_launch(void* const* d_in, const int* in_sizes, int n_in,
                              void* d_out, int out_size, void* d_ws, size_t ws_size,
                              hipStream_t stream) {
    const float* md   = (const float*)d_in[0];
    const float* dis  = (const float*)d_in[1];
    const float* res  = (const float*)d_in[2];
    const float* jloc = (const float*)d_in[3];
    const float* joff = (const float*)d_in[4];
    const float* feats= (const float*)d_in[5];
    const float* W1   = (const float*)d_in[6];
    const float* b1   = (const float*)d_in[7];
    const float* W2   = (const float*)d_in[8];
    const float* b2   = (const float*)d_in[9];
    const float* W3   = (const float*)d_in[10];
    const float* b3   = (const float*)d_in[11];
    float* out = (float*)d_out;

    char* ws = (char*)d_ws;
    size_t off = 0;
    auto alloc = [&](size_t bytes) {
        void* p = ws + off;
        off = (off + bytes + 255) & ~(size_t)255;
        return p;
    };
    float*  lines = (float*) alloc((size_t)NL * 4 * sizeof(float));
    ushort* ft    = (ushort*)alloc((size_t)HW * CC * 2);
    ushort* W1b   = (ushort*)alloc((size_t)1024 * 1024 * 2);
    ushort* W2b   = (ushort*)alloc((size_t)1024 * 1024 * 2);
    ushort* X     = (ushort*)alloc((size_t)NL * 1024 * 2);
    ushort* Y1    = (ushort*)alloc((size_t)NL * 1024 * 2);
    unsigned long long* cand = (unsigned long long*)alloc(4096 * 8);

    k_lines<<<NL / 256, 256, 0, stream>>>(md, dis, res, lines);
    k_transpose<<<dim3(CC / 32, HW / 32), dim3(32, 8), 0, stream>>>(feats, ft);
    k_cvt<<<(1024 * 1024) / 256, 256, 0, stream>>>(W1, W2, W1b, W2b, 1024 * 1024);
    k_pool<<<NL / 8, 128, 0, stream>>>(ft, lines, X);

    int ngrid = (NL / 256) * (1024 / 256);   // 768, divisible by 8
    k_gemm2<0><<<ngrid, 512, 0, stream>>>(X, W1b, b1, Y1, nullptr, nullptr, NL, 1024, 1024);
    k_init_logits<<<NL / 256, 256, 0, stream>>>(out, b3, NL);
    k_gemm2<1><<<ngrid, 512, 0, stream>>>(Y1, W2b, b2, nullptr, W3, out, NL, 1024, 1024);

    k_nms_topk<<<64, 256, 0, stream>>>(jloc, cand);
    k_topk_final<<<1, 1024, 0, stream>>>(cand, joff, out + NL);
}

// Round 8
// 370.361 us; speedup vs baseline: 1.1968x; 1.0111x over previous
//
#include <hip/hip_runtime.h>
#include <hip/hip_bf16.h>
#include <math.h>

#define HH 128
#define WW 128
#define HW 16384
#define NL 49152        // 3 * H * W lines
#define CC 128
#define NPTS0 32
#define NPTS1 8
#define PI_F 3.14159265358979323846f

typedef __attribute__((ext_vector_type(8))) short short8;
typedef __attribute__((ext_vector_type(4))) float f32x4;

__device__ __forceinline__ ushort f2bf(float f) {
    unsigned u = __builtin_bit_cast(unsigned, f);
    unsigned rounding = 0x7FFFu + ((u >> 16) & 1u);
    return (ushort)((u + rounding) >> 16);
}

__device__ __forceinline__ void gload_lds16(const void* gsrc, void* ldst) {
    __builtin_amdgcn_global_load_lds(
        (const __attribute__((address_space(1))) unsigned int*)gsrc,
        (__attribute__((address_space(3))) unsigned int*)ldst,
        16, 0, 0);
}

__device__ __forceinline__ void unpk8(uint4 d, float* f) {
    f[0] = __builtin_bit_cast(float, d.x << 16);
    f[1] = __builtin_bit_cast(float, d.x & 0xFFFF0000u);
    f[2] = __builtin_bit_cast(float, d.y << 16);
    f[3] = __builtin_bit_cast(float, d.y & 0xFFFF0000u);
    f[4] = __builtin_bit_cast(float, d.z << 16);
    f[5] = __builtin_bit_cast(float, d.z & 0xFFFF0000u);
    f[6] = __builtin_bit_cast(float, d.w << 16);
    f[7] = __builtin_bit_cast(float, d.w & 0xFFFF0000u);
}

// ---------------------------------------------------------------- lines
__global__ __launch_bounds__(256) void k_lines(
    const float* __restrict__ md, const float* __restrict__ dis,
    const float* __restrict__ res, float* __restrict__ lines)
{
    int g = blockIdx.x * 256 + threadIdx.x;
    if (g >= NL) return;
    int s = g / HW;              // 0,1,2 -> scale -1,0,1
    int pix = g - s * HW;
    float sf = (float)(s - 1);
    int y = pix >> 7, x = pix & 127;

    float md0 = md[pix], md1 = md[HW + pix], md2 = md[2 * HW + pix];
    float d = (dis[pix] + sf * res[pix]) * 5.0f;

    float md_ = (md0 - 0.5f) * (2.0f * PI_F);
    float st_ = md1 * (0.5f * PI_F);
    float ed_ = -md2 * (0.5f * PI_F);
    float cs_md = cosf(md_), ss_md = sinf(md_);
    float cs_st = fmaxf(cosf(st_), 0.001f);
    float ss_st = fmaxf(sinf(st_), 0.001f);
    float cs_ed = fmaxf(cosf(ed_), 0.001f);
    float ss_ed = fminf(sinf(ed_), -0.001f);
    float y_st = ss_st / cs_st;
    float y_ed = ss_ed / cs_ed;
    float x_st = (cs_md - ss_md * y_st) * d;
    float y_s  = (ss_md + cs_md * y_st) * d;
    float x_ed = (cs_md - ss_md * y_ed) * d;
    float y_e  = (ss_md + cs_md * y_ed) * d;

    float4 o;
    o.x = fminf(fmaxf(x_st + (float)x, 0.0f), 127.0f);
    o.y = fminf(fmaxf(y_s  + (float)y, 0.0f), 127.0f);
    o.z = fminf(fmaxf(x_ed + (float)x, 0.0f), 127.0f);
    o.w = fminf(fmaxf(y_e  + (float)y, 0.0f), 127.0f);
    ((float4*)lines)[g] = o;
}

// ---------------------------------- feats (C,HW) f32 -> (HW,C) bf16
__global__ void k_transpose(const float* __restrict__ in, ushort* __restrict__ out)
{
    __shared__ float tile[32][33];
    int cb = blockIdx.x;   // over C/32
    int pb = blockIdx.y;   // over HW/32
    int tx = threadIdx.x, ty = threadIdx.y;
#pragma unroll
    for (int j = 0; j < 32; j += 8)
        tile[ty + j][tx] = in[(size_t)(cb * 32 + ty + j) * HW + pb * 32 + tx];
    __syncthreads();
#pragma unroll
    for (int j = 0; j < 32; j += 8)
        out[(size_t)(pb * 32 + ty + j) * CC + cb * 32 + tx] = f2bf(tile[tx][ty + j]);
}

// ---------------------------------------------------------------- W -> bf16
__global__ void k_cvt(const float* __restrict__ a, const float* __restrict__ b,
                      ushort* __restrict__ oa, ushort* __restrict__ ob, int n)
{
    int i = blockIdx.x * 256 + threadIdx.x;
    if (i < n) { oa[i] = f2bf(a[i]); ob[i] = f2bf(b[i]); }
}

// ---------------------------------------------------------------- pooling
// block = 128 threads = 8 lines x 16 channel-groups-of-8.
__global__ __launch_bounds__(128, 4) void k_pool(
    const ushort* __restrict__ ft, const float* __restrict__ lines,
    ushort* __restrict__ X)
{
    __shared__ __align__(16) unsigned smeta[2048];   // 8 lines * 32 samples * 8 dwords
    const int t = threadIdx.x;
    const int l_loc = t >> 4, c8 = t & 15;
    const int gl0 = blockIdx.x * 8;

    // ---- phase A: per-(line,sample) meta, computed exactly once (2/thread)
#pragma unroll
    for (int e = 0; e < 2; ++e) {
        int s = t + e * 128;
        int ml = s >> 5, sp = s & 31;
        float4 L = ((const float4*)lines)[gl0 + ml];
        float tf = (float)sp * (1.0f / 31.0f);
        float omt = 1.0f - tf;
        float px = L.x * tf + L.z * omt - 0.5f;
        float py = L.y * tf + L.w * omt - 0.5f;
        float px0 = fminf(fmaxf(floorf(px), 0.0f), 127.0f);
        float py0 = fminf(fmaxf(floorf(py), 0.0f), 127.0f);
        float px1 = fminf(px0 + 1.0f, 127.0f);
        float py1 = fminf(py0 + 1.0f, 127.0f);
        int ix0 = (int)px0, iy0 = (int)py0, ix1 = (int)px1, iy1 = (int)py1;
        float4 wv;
        wv.x = (py1 - py) * (px1 - px);   // w00 (y0,x0)
        wv.y = (py  - py0) * (px1 - px);  // w10 (y1,x0)
        wv.z = (py1 - py) * (px  - px0);  // w01 (y0,x1)
        wv.w = (py  - py0) * (px  - px0); // w11 (y1,x1)
        int o00 = (iy0 * WW + ix0) * (CC * 2);
        int dx  = (ix1 - ix0) * (CC * 2);
        int dy  = (iy1 - iy0) * (WW * CC * 2);
        int4 ov;
        ov.x = o00;            // (y0,x0)
        ov.y = o00 + dy;       // (y1,x0)
        ov.z = o00 + dx;       // (y0,x1)
        ov.w = o00 + dy + dx;  // (y1,x1)
        *(float4*)&smeta[s * 8]     = wv;
        *(int4*)  &smeta[s * 8 + 4] = ov;
    }
    __syncthreads();

    // ---- phase B: gather (16B) + bilinear + max-pool
    const unsigned coff = (unsigned)(c8 * 16);
    const char* fbase = (const char*)ft;
    float m[8][8];
#pragma unroll
    for (int ch = 0; ch < 8; ++ch)
#pragma unroll
        for (int g = 0; g < 8; ++g) m[ch][g] = -INFINITY;

#pragma unroll
    for (int g = 0; g < 8; ++g) {
#pragma unroll
        for (int j = 0; j < 4; ++j) {
            const unsigned* mp = &smeta[(l_loc * 32 + g * 4 + j) * 8];
            float4 wv = *(const float4*)mp;
            int4  ov = *(const int4*)(mp + 4);
            uint4 d00 = *(const uint4*)(fbase + ((unsigned)ov.x + coff));
            uint4 d10 = *(const uint4*)(fbase + ((unsigned)ov.y + coff));
            uint4 d01 = *(const uint4*)(fbase + ((unsigned)ov.z + coff));
            uint4 d11 = *(const uint4*)(fbase + ((unsigned)ov.w + coff));
            float f00[8], f10[8], f01[8], f11[8];
            unpk8(d00, f00); unpk8(d10, f10); unpk8(d01, f01); unpk8(d11, f11);
#pragma unroll
            for (int ch = 0; ch < 8; ++ch) {
                float v = f00[ch] * wv.x + f10[ch] * wv.y
                        + f01[ch] * wv.z + f11[ch] * wv.w;
                m[ch][g] = fmaxf(m[ch][g], v);
            }
        }
    }

    ushort* Xp = X + (size_t)(gl0 + l_loc) * 1024 + c8 * 64;
#pragma unroll
    for (int ch = 0; ch < 8; ++ch) {
        short8 pk;
#pragma unroll
        for (int g = 0; g < 8; ++g) pk[g] = (short)f2bf(m[ch][g]);
        *(short8*)(Xp + ch * 8) = pk;
    }
}

// ---------------------------------------------------------------- GEMM 256x256
// Deep-pipelined: BK=32, 4-slot LDS ring, counted vmcnt(6), ONE raw s_barrier
// per K-tile, T2 granule swizzle, T5 setprio, T1 XCD swizzle.
// SWAPPED-OPERAND MFMA: acc[m][n] = mfma(bq[n], a[m], .) so each lane holds
// 4 consecutive Y-COLUMNS (j) of one row: lane l -> row = rbase+(l&15),
// cols = cbase + (l>>4)*4 + j. Epilogues vectorize (8B stores / 16-lane atomics).
#define NT 32            // K / 32
template<int EPI>
__global__ __launch_bounds__(512, 2) void k_gemm2(
    const ushort* __restrict__ A, const ushort* __restrict__ B,
    const float* __restrict__ bias, ushort* __restrict__ Y,
    const float* __restrict__ w3, float* __restrict__ logits,
    int M, int N, int K)
{
    __shared__ __align__(16) ushort lds[65536];   // A: [0,32768), B: [32768,65536)
    const int tid = threadIdx.x;
    const int w = tid >> 6, l = tid & 63;
    const int lr = l & 15, kq = l >> 4;
    const int wm = w >> 2, wn = w & 3;

    // T1: bijective XCD swizzle (gridDim.x % 8 == 0)
    const int nwg = gridDim.x;
    const int cpx = nwg >> 3;
    const int swz = (blockIdx.x & 7) * cpx + (blockIdx.x >> 3);
    const int nbm = M >> 8;
    const int m_blk = swz % nbm;
    const int n_blk = swz / nbm;
    const int m0 = m_blk << 8, n0 = n_blk << 8;

    // staging source precompute (T2 inverse swizzle on source granule)
    const int G0 = tid, G1 = 512 + tid;
    const int r0 = G0 >> 2, r1 = G1 >> 2;
    const int g0 = (G0 & 3) ^ ((r0 >> 1) & 3);
    const int g1 = (G1 & 3) ^ ((r1 >> 1) & 3);
    const ushort* sA0 = A + (size_t)(m0 + r0) * K + g0 * 8;
    const ushort* sA1 = A + (size_t)(m0 + r1) * K + g1 * 8;
    const ushort* sB0 = B + (size_t)(n0 + r0) * K + g0 * 8;
    const ushort* sB1 = B + (size_t)(n0 + r1) * K + g1 * 8;
    ushort* dA0 = &lds[G0 * 8];
    ushort* dA1 = &lds[G1 * 8];
    ushort* dB0 = &lds[32768 + G0 * 8];
    ushort* dB1 = &lds[32768 + G1 * 8];

#define STAGE_A(tp) { int sb_ = ((tp) & 3) * 8192; \
    gload_lds16(sA0 + (tp) * 32, dA0 + sb_); \
    gload_lds16(sA1 + (tp) * 32, dA1 + sb_); }
#define STAGE_B(tp) { int sb_ = ((tp) & 3) * 8192; \
    gload_lds16(sB0 + (tp) * 32, dB0 + sb_); \
    gload_lds16(sB1 + (tp) * 32, dB1 + sb_); }
#define SBAR  { __builtin_amdgcn_sched_barrier(0); __builtin_amdgcn_s_barrier(); \
                __builtin_amdgcn_sched_barrier(0); }

    // swizzled ds_read offsets (ushort units)
    int aidx[8], bidx[4];
#pragma unroll
    for (int m = 0; m < 8; ++m) {
        int r = wm * 128 + m * 16 + lr;
        int g = kq ^ ((r >> 1) & 3);
        aidx[m] = r * 32 + g * 8;
    }
#pragma unroll
    for (int n = 0; n < 4; ++n) {
        int r = wn * 64 + n * 16 + lr;
        int g = kq ^ ((r >> 1) & 3);
        bidx[n] = 32768 + r * 32 + g * 8;
    }

    f32x4 acc[8][4] = {};

    // prologue: A0 B0 A1 B1 A2 (10 loads) -> tile0 ready, 6 in flight
    STAGE_A(0); STAGE_B(0); STAGE_A(1); STAGE_B(1); STAGE_A(2);
    asm volatile("s_waitcnt vmcnt(6)" ::: "memory");
    SBAR;

    for (int t = 0; t < NT; ++t) {
        const int sb = (t & 3) * 8192;
        short8 bq0 = *(const short8*)&lds[sb + bidx[0]];
        short8 bq1 = *(const short8*)&lds[sb + bidx[1]];
        short8 bq2 = *(const short8*)&lds[sb + bidx[2]];
        short8 bq3 = *(const short8*)&lds[sb + bidx[3]];
        short8 a[8];
#pragma unroll
        for (int m = 0; m < 8; ++m)
            a[m] = *(const short8*)&lds[sb + aidx[m]];
        if (t + 2 < NT) STAGE_B(t + 2);
        if (t + 3 < NT) STAGE_A(t + 3);
        __builtin_amdgcn_s_setprio(1);
#pragma unroll
        for (int m = 0; m < 8; ++m) {
            acc[m][0] = __builtin_amdgcn_mfma_f32_16x16x32_bf16(bq0, a[m], acc[m][0], 0, 0, 0);
            acc[m][1] = __builtin_amdgcn_mfma_f32_16x16x32_bf16(bq1, a[m], acc[m][1], 0, 0, 0);
            acc[m][2] = __builtin_amdgcn_mfma_f32_16x16x32_bf16(bq2, a[m], acc[m][2], 0, 0, 0);
            acc[m][3] = __builtin_amdgcn_mfma_f32_16x16x32_bf16(bq3, a[m], acc[m][3], 0, 0, 0);
        }
        __builtin_amdgcn_s_setprio(0);
        if (t < NT - 3) {
            asm volatile("s_waitcnt vmcnt(6)" ::: "memory");
        } else {
            asm volatile("s_waitcnt vmcnt(0)" ::: "memory");
        }
        SBAR;
    }
#undef STAGE_A
#undef STAGE_B
#undef SBAR

    // ---------------- epilogue (swapped layout: row = rbase+lr, cols j-quad)
    if (EPI == 0) {
#pragma unroll
        for (int n = 0; n < 4; ++n) {
            int cbase = n0 + wn * 64 + n * 16 + kq * 4;
            float4 bv4 = *(const float4*)&bias[cbase];
#pragma unroll
            for (int m = 0; m < 8; ++m) {
                int row = m0 + wm * 128 + m * 16 + lr;
                ushort4 pk;
                pk.x = f2bf(fmaxf(acc[m][n][0] + bv4.x, 0.0f));
                pk.y = f2bf(fmaxf(acc[m][n][1] + bv4.y, 0.0f));
                pk.z = f2bf(fmaxf(acc[m][n][2] + bv4.z, 0.0f));
                pk.w = f2bf(fmaxf(acc[m][n][3] + bv4.w, 0.0f));
                *(ushort4*)(Y + (size_t)row * N + cbase) = pk;
            }
        }
    } else {
        float4 bv4[4], w34[4];
#pragma unroll
        for (int n = 0; n < 4; ++n) {
            int cbase = n0 + wn * 64 + n * 16 + kq * 4;
            bv4[n] = *(const float4*)&bias[cbase];
            w34[n] = *(const float4*)&w3[cbase];
        }
#pragma unroll
        for (int m = 0; m < 8; ++m) {
            float s = 0.0f;
#pragma unroll
            for (int n = 0; n < 4; ++n) {
                s += fmaxf(acc[m][n][0] + bv4[n].x, 0.0f) * w34[n].x;
                s += fmaxf(acc[m][n][1] + bv4[n].y, 0.0f) * w34[n].y;
                s += fmaxf(acc[m][n][2] + bv4[n].z, 0.0f) * w34[n].z;
                s += fmaxf(acc[m][n][3] + bv4[n].w, 0.0f) * w34[n].w;
            }
            s += __shfl_xor(s, 16, 64);
            s += __shfl_xor(s, 32, 64);
            if (kq == 0)
                atomicAdd(&logits[m0 + wm * 128 + m * 16 + lr], s);
        }
    }
}

// ---------------------------------------------------------------- logits = b3
__global__ void k_init_logits(float* __restrict__ logits, const float* __restrict__ b3, int n)
{
    int i = blockIdx.x * 256 + threadIdx.x;
    if (i < n) logits[i] = b3[0];
}

// --------------------------------------------- NMS + per-chunk top-50
__global__ __launch_bounds__(256) void k_nms_topk(
    const float* __restrict__ jloc, unsigned long long* __restrict__ cand)
{
    __shared__ unsigned long long sk[256];
    const int t = threadIdx.x;
    const int idx = blockIdx.x * 256 + t;      // 64 chunks x 2 rows
    const int y = idx >> 7, x = idx & 127;
    float cv = jloc[idx];
    float m = cv;
    for (int dy = -1; dy <= 1; ++dy) {
        int yy = y + dy;
        if (yy < 0 || yy > 127) continue;
        for (int dx = -1; dx <= 1; ++dx) {
            int xx = x + dx;
            if (xx < 0 || xx > 127) continue;
            m = fmaxf(m, jloc[(yy << 7) + xx]);
        }
    }
    float nv = (cv == m) ? cv : 0.0f;
    unsigned vb = __builtin_bit_cast(unsigned, nv);
    sk[t] = ((unsigned long long)vb << 32) | (unsigned)(0xFFFFFFFFu - idx);
    __syncthreads();
    for (int k = 2; k <= 256; k <<= 1) {
        for (int j = k >> 1; j >= 1; j >>= 1) {
            int ixj = t ^ j;
            if (ixj > t) {
                unsigned long long a = sk[t], b = sk[ixj];
                bool up = ((t & k) == 0);
                if (up ? (a < b) : (a > b)) { sk[t] = b; sk[ixj] = a; }
            }
            __syncthreads();
        }
    }
    if (t < 64) cand[blockIdx.x * 64 + t] = (t < 50) ? sk[t] : 0ull;
}

// --------------------------------------------- merge 64x50 -> top-50 + junctions
__global__ __launch_bounds__(1024) void k_topk_final(
    const unsigned long long* __restrict__ cand,
    const float* __restrict__ joff, float* __restrict__ outj)
{
    __shared__ unsigned long long sk[4096];
    const int t = threadIdx.x;
#pragma unroll
    for (int e = 0; e < 4; ++e) sk[t + (e << 10)] = cand[t + (e << 10)];
    __syncthreads();
    for (int k = 2; k <= 4096; k <<= 1) {
        for (int j = k >> 1; j >= 1; j >>= 1) {
#pragma unroll
            for (int e = 0; e < 4; ++e) {
                int i = t + (e << 10);
                int ixj = i ^ j;
                if (ixj > i) {
                    unsigned long long a = sk[i], b = sk[ixj];
                    bool up = ((i & k) == 0);
                    if (up ? (a < b) : (a > b)) { sk[i] = b; sk[ixj] = a; }
                }
            }
            __syncthreads();
        }
    }
    if (t < 50) {
        unsigned long long kk = sk[t];
        unsigned idx = 0xFFFFFFFFu - (unsigned)(kk & 0xFFFFFFFFull);
        float val = __builtin_bit_cast(float, (unsigned)(kk >> 32));
        int y = idx >> 7, x = idx & 127;
        outj[2 * t]     = (float)x + joff[idx]      + 0.5f;
        outj[2 * t + 1] = (float)y + joff[HW + idx] + 0.5f;
        outj[100 + t]   = val;
    }
}

// ---------------------------------------------------------------- launch
extern "C" void kernel_launch(void* const* d_in, const int* in_sizes, int n_in,
                              void* d_out, int out_size, void* d_ws, size_t ws_size,
                              hipStream_t stream) {
    const float* md   = (const float*)d_in[0];
    const float* dis  = (const float*)d_in[1];
    const float* res  = (const float*)d_in[2];
    const float* jloc = (const float*)d_in[3];
    const float* joff = (const float*)d_in[4];
    const float* feats= (const float*)d_in[5];
    const float* W1   = (const float*)d_in[6];
    const float* b1   = (const float*)d_in[7];
    const float* W2   = (const float*)d_in[8];
    const float* b2   = (const float*)d_in[9];
    const float* W3   = (const float*)d_in[10];
    const float* b3   = (const float*)d_in[11];
    float* out = (float*)d_out;

    char* ws = (char*)d_ws;
    size_t off = 0;
    auto alloc = [&](size_t bytes) {
        void* p = ws + off;
        off = (off + bytes + 255) & ~(size_t)255;
        return p;
    };
    float*  lines = (float*) alloc((size_t)NL * 4 * sizeof(float));
    ushort* ft    = (ushort*)alloc((size_t)HW * CC * 2);
    ushort* W1b   = (ushort*)alloc((size_t)1024 * 1024 * 2);
    ushort* W2b   = (ushort*)alloc((size_t)1024 * 1024 * 2);
    ushort* X     = (ushort*)alloc((size_t)NL * 1024 * 2);
    ushort* Y1    = (ushort*)alloc((size_t)NL * 1024 * 2);
    unsigned long long* cand = (unsigned long long*)alloc(4096 * 8);

    k_lines<<<NL / 256, 256, 0, stream>>>(md, dis, res, lines);
    k_transpose<<<dim3(CC / 32, HW / 32), dim3(32, 8), 0, stream>>>(feats, ft);
    k_cvt<<<(1024 * 1024) / 256, 256, 0, stream>>>(W1, W2, W1b, W2b, 1024 * 1024);
    k_pool<<<NL / 8, 128, 0, stream>>>(ft, lines, X);

    int ngrid = (NL / 256) * (1024 / 256);   // 768, divisible by 8
    k_gemm2<0><<<ngrid, 512, 0, stream>>>(X, W1b, b1, Y1, nullptr, nullptr, NL, 1024, 1024);
    k_init_logits<<<NL / 256, 256, 0, stream>>>(out, b3, NL);
    k_gemm2<1><<<ngrid, 512, 0, stream>>>(Y1, W2b, b2, nullptr, W3, out, NL, 1024, 1024);

    k_nms_topk<<<64, 256, 0, stream>>>(jloc, cand);
    k_topk_final<<<1, 1024, 0, stream>>>(cand, joff, out + NL);
}